// Round 6
// baseline (8069.584 us; speedup 1.0000x reference)
//
#include <hip/hip_runtime.h>

// Echo State Network, T=1024 sequential steps of r' = 0.5 r + 0.5 tanh(W r + Win u).
// Persistent kernel. W pinned in hard-named AGPRs (verified r4: VGPR_Count=128).
//
// Round-6: r5 (relaxed atomics) got 23->4.1 ms; remaining cost is the two-hop
// barrier (flag round-trip + data round-trip) plus the pre-publish drain barrier.
// Fix: SELF-TAGGED DATA. Each r value is an 8B atom (float value, uint step tag);
// producers publish per-WAVE (no WG drain barrier), consumers poll the data
// directly (one global hop). Tag check is EXACT (== t): poison 0xAAAAAAAA and
// stale tags from earlier replays can never false-positive. pred is computed as
// 8 per-wave partials in WG0 (LDS psums), finalized one iteration later.
//
// d_ws layout: [0, 65536): ull rbuf2[2][4096]  (tagged, double-buffered r)

#define T_STEPS 1024
#define R_DIM   4096
#define N_WG    256
#define N_THR   512
#define ROWS_PER_WG 16
#define K_CHUNKS 16          // R_DIM / (64 lanes * 4 floats)

#define AGENT __HIP_MEMORY_SCOPE_AGENT

typedef unsigned long long ull;
typedef unsigned int uint32;

__device__ __forceinline__ float fast_tanh(float x) {
    float ax = fabsf(x);
    float e  = __expf(-2.0f * ax);
    float t  = (1.0f - e) / (1.0f + e);
    return copysignf(t, x);
}

// Store one float4 into four named physical AGPRs.
#define WST4(A0, A1, A2, A3, vec)                                              \
    asm volatile("v_accvgpr_write_b32 a" #A0 ", %0\n\t"                        \
                 "v_accvgpr_write_b32 a" #A1 ", %1\n\t"                        \
                 "v_accvgpr_write_b32 a" #A2 ", %2\n\t"                        \
                 "v_accvgpr_write_b32 a" #A3 ", %3"                            \
                 :: "v"((vec).x), "v"((vec).y), "v"((vec).z), "v"((vec).w)     \
                 : "a" #A0, "a" #A1, "a" #A2, "a" #A3)

// One K-chunk of the two-row matvec: read 4+4 W values from AGPRs, FMA with rv.
#define MV2(c, A0, A1, A2, A3, B0, B1, B2, B3)                                 \
    do {                                                                       \
        float4 rv = rv4[(c) * 64 + lane];                                      \
        float w0, w1, w2, w3, u0, u1, u2, u3;                                  \
        asm volatile("v_accvgpr_read_b32 %0, a" #A0 "\n\t"                     \
                     "v_accvgpr_read_b32 %1, a" #A1 "\n\t"                     \
                     "v_accvgpr_read_b32 %2, a" #A2 "\n\t"                     \
                     "v_accvgpr_read_b32 %3, a" #A3 "\n\t"                     \
                     "v_accvgpr_read_b32 %4, a" #B0 "\n\t"                     \
                     "v_accvgpr_read_b32 %5, a" #B1 "\n\t"                     \
                     "v_accvgpr_read_b32 %6, a" #B2 "\n\t"                     \
                     "v_accvgpr_read_b32 %7, a" #B3                            \
                     : "=v"(w0), "=v"(w1), "=v"(w2), "=v"(w3),                 \
                       "=v"(u0), "=v"(u1), "=v"(u2), "=v"(u3));                \
        accA.x = fmaf(w0, rv.x, accA.x);                                       \
        accA.y = fmaf(w1, rv.y, accA.y);                                       \
        accA.z = fmaf(w2, rv.z, accA.z);                                       \
        accA.w = fmaf(w3, rv.w, accA.w);                                       \
        accB.x = fmaf(u0, rv.x, accB.x);                                       \
        accB.y = fmaf(u1, rv.y, accB.y);                                       \
        accB.z = fmaf(u2, rv.z, accB.z);                                       \
        accB.w = fmaf(u3, rv.w, accB.w);                                       \
    } while (0)

__global__ __launch_bounds__(N_THR, 2)
void esn_persistent(const float* __restrict__ batch,
                    const float* __restrict__ Win,
                    const float* __restrict__ W,
                    const float* __restrict__ Wout,
                    float* __restrict__ out,
                    ull*   __restrict__ rbuf2)
{
    __shared__ __align__(16) float r_lds[R_DIM];   // current r(t)
    __shared__ float b_lds[T_STEPS];               // input sequence
    __shared__ float psum_lds[8];                  // WG0 pred partials

    const int tid  = threadIdx.x;
    const int wid  = blockIdx.x;
    const int wave = tid >> 6;
    const int lane = tid & 63;
    const int rowA = wid * ROWS_PER_WG + wave * 2; // this wave's two W rows
    const int rowB = rowA + 1;

    for (int i = tid; i < R_DIM; i += N_THR) r_lds[i] = 0.0f;   // r(0) = 0
    for (int i = tid; i < T_STEPS; i += N_THR) b_lds[i] = batch[i];

    // Pin W rows in physical AGPRs. Lane's chunk c covers k = c*256 + lane*4.
    {
        const float4* pA = reinterpret_cast<const float4*>(W + (size_t)rowA * R_DIM);
        const float4* pB = reinterpret_cast<const float4*>(W + (size_t)rowB * R_DIM);
        float4 v;
        v = pA[ 0 * 64 + lane]; WST4(  0,   1,   2,   3, v);
        v = pA[ 1 * 64 + lane]; WST4(  4,   5,   6,   7, v);
        v = pA[ 2 * 64 + lane]; WST4(  8,   9,  10,  11, v);
        v = pA[ 3 * 64 + lane]; WST4( 12,  13,  14,  15, v);
        v = pA[ 4 * 64 + lane]; WST4( 16,  17,  18,  19, v);
        v = pA[ 5 * 64 + lane]; WST4( 20,  21,  22,  23, v);
        v = pA[ 6 * 64 + lane]; WST4( 24,  25,  26,  27, v);
        v = pA[ 7 * 64 + lane]; WST4( 28,  29,  30,  31, v);
        v = pA[ 8 * 64 + lane]; WST4( 32,  33,  34,  35, v);
        v = pA[ 9 * 64 + lane]; WST4( 36,  37,  38,  39, v);
        v = pA[10 * 64 + lane]; WST4( 40,  41,  42,  43, v);
        v = pA[11 * 64 + lane]; WST4( 44,  45,  46,  47, v);
        v = pA[12 * 64 + lane]; WST4( 48,  49,  50,  51, v);
        v = pA[13 * 64 + lane]; WST4( 52,  53,  54,  55, v);
        v = pA[14 * 64 + lane]; WST4( 56,  57,  58,  59, v);
        v = pA[15 * 64 + lane]; WST4( 60,  61,  62,  63, v);
        v = pB[ 0 * 64 + lane]; WST4( 64,  65,  66,  67, v);
        v = pB[ 1 * 64 + lane]; WST4( 68,  69,  70,  71, v);
        v = pB[ 2 * 64 + lane]; WST4( 72,  73,  74,  75, v);
        v = pB[ 3 * 64 + lane]; WST4( 76,  77,  78,  79, v);
        v = pB[ 4 * 64 + lane]; WST4( 80,  81,  82,  83, v);
        v = pB[ 5 * 64 + lane]; WST4( 84,  85,  86,  87, v);
        v = pB[ 6 * 64 + lane]; WST4( 88,  89,  90,  91, v);
        v = pB[ 7 * 64 + lane]; WST4( 92,  93,  94,  95, v);
        v = pB[ 8 * 64 + lane]; WST4( 96,  97,  98,  99, v);
        v = pB[ 9 * 64 + lane]; WST4(100, 101, 102, 103, v);
        v = pB[10 * 64 + lane]; WST4(104, 105, 106, 107, v);
        v = pB[11 * 64 + lane]; WST4(108, 109, 110, 111, v);
        v = pB[12 * 64 + lane]; WST4(112, 113, 114, 115, v);
        v = pB[13 * 64 + lane]; WST4(116, 117, 118, 119, v);
        v = pB[14 * 64 + lane]; WST4(120, 121, 122, 123, v);
        v = pB[15 * 64 + lane]; WST4(124, 125, 126, 127, v);
    }
    const float winA0 = Win[2 * rowA], winA1 = Win[2 * rowA + 1];
    const float winB0 = Win[2 * rowB], winB1 = Win[2 * rowB + 1];

    __syncthreads();

    const float4* rv4 = reinterpret_cast<const float4*>(r_lds);

    for (int t = 0; t < T_STEPS; ++t) {
        if (t > 0) {
            // Poll tagged data directly: 8 units/thread, all loads in flight first.
            const ull* src = rbuf2 + (size_t)(t & 1) * R_DIM;
            const uint32 tagexp = (uint32)t;
            ull v0, v1, v2, v3, v4, v5, v6, v7;
            v0 = __hip_atomic_load(src + tid + 0 * 512, __ATOMIC_RELAXED, AGENT);
            v1 = __hip_atomic_load(src + tid + 1 * 512, __ATOMIC_RELAXED, AGENT);
            v2 = __hip_atomic_load(src + tid + 2 * 512, __ATOMIC_RELAXED, AGENT);
            v3 = __hip_atomic_load(src + tid + 3 * 512, __ATOMIC_RELAXED, AGENT);
            v4 = __hip_atomic_load(src + tid + 4 * 512, __ATOMIC_RELAXED, AGENT);
            v5 = __hip_atomic_load(src + tid + 5 * 512, __ATOMIC_RELAXED, AGENT);
            v6 = __hip_atomic_load(src + tid + 6 * 512, __ATOMIC_RELAXED, AGENT);
            v7 = __hip_atomic_load(src + tid + 7 * 512, __ATOMIC_RELAXED, AGENT);
            #define RETRY(vk, k)                                                   \
                while ((uint32)((vk) >> 32) != tagexp) {                           \
                    __builtin_amdgcn_s_sleep(1);                                   \
                    (vk) = __hip_atomic_load(src + tid + (k) * 512,                \
                                             __ATOMIC_RELAXED, AGENT);             \
                }
            RETRY(v0, 0) RETRY(v1, 1) RETRY(v2, 2) RETRY(v3, 3)
            RETRY(v4, 4) RETRY(v5, 5) RETRY(v6, 6) RETRY(v7, 7)
            #undef RETRY
            __syncthreads();   // all prior-step LDS reads (matvec, psums) done

            // Finalize pred[t-2] from last iteration's psums (WG0, one thread).
            if (wid == 0 && tid == 0 && t >= 2) {
                float s = ((psum_lds[0] + psum_lds[1]) + (psum_lds[2] + psum_lds[3]))
                        + ((psum_lds[4] + psum_lds[5]) + (psum_lds[6] + psum_lds[7]));
                out[t - 2] = s + fmaf(Wout[1], b_lds[t - 2], Wout[0]);
            }

            // Stage values into LDS (conflict-free: adjacent lanes adjacent words).
            r_lds[tid + 0 * 512] = __uint_as_float((uint32)v0);
            r_lds[tid + 1 * 512] = __uint_as_float((uint32)v1);
            r_lds[tid + 2 * 512] = __uint_as_float((uint32)v2);
            r_lds[tid + 3 * 512] = __uint_as_float((uint32)v3);
            r_lds[tid + 4 * 512] = __uint_as_float((uint32)v4);
            r_lds[tid + 5 * 512] = __uint_as_float((uint32)v5);
            r_lds[tid + 6 * 512] = __uint_as_float((uint32)v6);
            r_lds[tid + 7 * 512] = __uint_as_float((uint32)v7);
            __syncthreads();
        }

        // y = W r(t) for this wave's two rows (W in AGPRs, r broadcast from LDS).
        float4 accA = make_float4(0.f, 0.f, 0.f, 0.f);
        float4 accB = make_float4(0.f, 0.f, 0.f, 0.f);
        MV2( 0,   0,   1,   2,   3,  64,  65,  66,  67);
        MV2( 1,   4,   5,   6,   7,  68,  69,  70,  71);
        MV2( 2,   8,   9,  10,  11,  72,  73,  74,  75);
        MV2( 3,  12,  13,  14,  15,  76,  77,  78,  79);
        MV2( 4,  16,  17,  18,  19,  80,  81,  82,  83);
        MV2( 5,  20,  21,  22,  23,  84,  85,  86,  87);
        MV2( 6,  24,  25,  26,  27,  88,  89,  90,  91);
        MV2( 7,  28,  29,  30,  31,  92,  93,  94,  95);
        MV2( 8,  32,  33,  34,  35,  96,  97,  98,  99);
        MV2( 9,  36,  37,  38,  39, 100, 101, 102, 103);
        MV2(10,  40,  41,  42,  43, 104, 105, 106, 107);
        MV2(11,  44,  45,  46,  47, 108, 109, 110, 111);
        MV2(12,  48,  49,  50,  51, 112, 113, 114, 115);
        MV2(13,  52,  53,  54,  55, 116, 117, 118, 119);
        MV2(14,  56,  57,  58,  59, 120, 121, 122, 123);
        MV2(15,  60,  61,  62,  63, 124, 125, 126, 127);

        float sA = (accA.x + accA.y) + (accA.z + accA.w);
        float sB = (accB.x + accB.y) + (accB.z + accB.w);
        #pragma unroll
        for (int m = 1; m < 64; m <<= 1) {
            sA += __shfl_xor(sA, m);
            sB += __shfl_xor(sB, m);
        }

        // Per-WAVE publish: tagged 8B atoms, no drain barrier needed.
        if (lane == 0) {
            float bt = b_lds[t];
            float xA = fast_tanh(sA + fmaf(winA1, bt, winA0));
            float xB = fast_tanh(sB + fmaf(winB1, bt, winB0));
            float rnA = 0.5f * (r_lds[rowA] + xA);
            float rnB = 0.5f * (r_lds[rowB] + xB);
            ull uA = ((ull)(uint32)(t + 1) << 32) | __float_as_uint(rnA);
            ull uB = ((ull)(uint32)(t + 1) << 32) | __float_as_uint(rnB);
            ull* dst = rbuf2 + (size_t)((t + 1) & 1) * R_DIM;
            __hip_atomic_store(dst + rowA, uA, __ATOMIC_RELAXED, AGENT);
            __hip_atomic_store(dst + rowB, uB, __ATOMIC_RELAXED, AGENT);
        }

        // WG0: pred[t-1] partials over this wave's 512-element slice of r(t).
        if (wid == 0 && t >= 1) {
            const float* wr = Wout + 2;
            float s = 0.0f;
            #pragma unroll
            for (int cc = 0; cc < 2; ++cc) {
                int c = wave * 2 + cc;
                int k = c * 256 + lane * 4;
                float2 wa = *reinterpret_cast<const float2*>(wr + k);
                float2 wb = *reinterpret_cast<const float2*>(wr + k + 2);
                float4 rv = rv4[c * 64 + lane];
                s = fmaf(wa.x, rv.x, s);
                s = fmaf(wa.y, rv.y, s);
                s = fmaf(wb.x, rv.z, s);
                s = fmaf(wb.y, rv.w, s);
            }
            #pragma unroll
            for (int m = 1; m < 64; m <<= 1) s += __shfl_xor(s, m);
            if (lane == 0) psum_lds[wave] = s;
        }
    }

    // Epilogue (WG0 only): out[T-2] from last psums; out[T-1] from r(T).
    if (wid == 0) {
        __syncthreads();
        if (tid == 0) {
            float s = ((psum_lds[0] + psum_lds[1]) + (psum_lds[2] + psum_lds[3]))
                    + ((psum_lds[4] + psum_lds[5]) + (psum_lds[6] + psum_lds[7]));
            out[T_STEPS - 2] = s + fmaf(Wout[1], b_lds[T_STEPS - 2], Wout[0]);
        }
        // Stage r(T) (tag T_STEPS, buffer index T_STEPS&1 == 0).
        const ull* src = rbuf2 + (size_t)(T_STEPS & 1) * R_DIM;
        #pragma unroll
        for (int k = 0; k < 8; ++k) {
            ull v;
            do {
                v = __hip_atomic_load(src + tid + k * 512, __ATOMIC_RELAXED, AGENT);
                if ((uint32)(v >> 32) == (uint32)T_STEPS) break;
                __builtin_amdgcn_s_sleep(1);
            } while (true);
            r_lds[tid + k * 512] = __uint_as_float((uint32)v);
        }
        __syncthreads();
        if (wave == 0) {
            const float* wr = Wout + 2;
            float s = 0.0f;
            #pragma unroll
            for (int c = 0; c < K_CHUNKS; ++c) {
                int k = c * 256 + lane * 4;
                float2 wa = *reinterpret_cast<const float2*>(wr + k);
                float2 wb = *reinterpret_cast<const float2*>(wr + k + 2);
                float4 rv = rv4[c * 64 + lane];
                s = fmaf(wa.x, rv.x, s);
                s = fmaf(wa.y, rv.y, s);
                s = fmaf(wb.x, rv.z, s);
                s = fmaf(wb.y, rv.w, s);
            }
            #pragma unroll
            for (int m = 1; m < 64; m <<= 1) s += __shfl_xor(s, m);
            if (lane == 0)
                out[T_STEPS - 1] = s + fmaf(Wout[1], b_lds[T_STEPS - 1], Wout[0]);
        }
    }
}

extern "C" void kernel_launch(void* const* d_in, const int* in_sizes, int n_in,
                              void* d_out, int out_size, void* d_ws, size_t ws_size,
                              hipStream_t stream) {
    (void)in_sizes; (void)n_in; (void)out_size; (void)ws_size;
    const float* batch = (const float*)d_in[0];   // (1024,1,1)
    const float* Win   = (const float*)d_in[1];   // (4096,2) row-major
    const float* W     = (const float*)d_in[2];   // (4096,4096) row-major
    const float* Wout  = (const float*)d_in[3];   // (1,4098)
    float* out  = (float*)d_out;                  // (1024,1)
    ull*   rbuf2 = (ull*)d_ws;                    // 2*4096 tagged units (64 KB)

    // No init needed: tag check is exact-match; poison 0xAAAAAAAA and stale tags
    // from previous replays can never equal the expected tag before the true
    // store of this run arrives (in-run tags per slot are unique: t, t+2, ...).

    // grid=256 WGs x 512 thr (8 waves = 2 waves/SIMD; 128 AGPR + ~64 VGPR fits).
    // grid == CU count => all WGs co-resident for the data-tag spin.
    esn_persistent<<<dim3(N_WG), dim3(N_THR), 0, stream>>>(
        batch, Win, W, Wout, out, rbuf2);
}

// Round 7
// 5969.070 us; speedup vs baseline: 1.3519x; 1.3519x over previous
//
#include <hip/hip_runtime.h>

// Echo State Network, T=1024 sequential steps of r' = 0.5 r + 0.5 tanh(W r + Win u).
// Persistent kernel. W pinned in hard-named AGPRs (verified: VGPR_Count=128 in r4).
//
// Sync design (r7): r6's poll-the-data scheme regressed (FETCH 465 MB: 256-line
// retry storm). Back to r5's topology — small shared flag region + exactly-once
// payload reads — minus two serial hops:
//  * each thread polls only its OWN 4 producer flags (unit i=tid+512j is rows
//    {2i,2i+1}, produced by WG i/8 = tid/8 + 64j), then stages its 4 units with
//    no barrier in between;
//  * barrier A (post-stage) doubles as the collective proof that ALL 256 flags
//    >= t (union of the WG's poll sets = flags[0..255]), so the publish that
//    follows it cannot overwrite a buffer any WG is still reading (2-buffer
//    ping-pong safety);
//  * 2 barriers/step total (A post-stage, B pre-flag drain); pred psums off
//    the critical path (written before B, finalized by tid0 after the flag store).
//
// d_ws layout: [0, 32768): float rbuf[2][4096] (double-buffered r, 8B-paired rows)
//              [32768, 33792): int flags[256]  (last published step per WG)

#define T_STEPS 1024
#define R_DIM   4096
#define N_WG    256
#define N_THR   512
#define ROWS_PER_WG 16
#define K_CHUNKS 16          // R_DIM / (64 lanes * 4 floats)

#define AGENT __HIP_MEMORY_SCOPE_AGENT

typedef unsigned long long ull;
typedef unsigned int uint32;

__device__ __forceinline__ float fast_tanh(float x) {
    float ax = fabsf(x);
    float e  = __expf(-2.0f * ax);
    float t  = (1.0f - e) / (1.0f + e);
    return copysignf(t, x);
}

// Store one float4 into four named physical AGPRs.
#define WST4(A0, A1, A2, A3, vec)                                              \
    asm volatile("v_accvgpr_write_b32 a" #A0 ", %0\n\t"                        \
                 "v_accvgpr_write_b32 a" #A1 ", %1\n\t"                        \
                 "v_accvgpr_write_b32 a" #A2 ", %2\n\t"                        \
                 "v_accvgpr_write_b32 a" #A3 ", %3"                            \
                 :: "v"((vec).x), "v"((vec).y), "v"((vec).z), "v"((vec).w)     \
                 : "a" #A0, "a" #A1, "a" #A2, "a" #A3)

// One K-chunk of the two-row matvec: read 4+4 W values from AGPRs, FMA with rv.
#define MV2(c, A0, A1, A2, A3, B0, B1, B2, B3)                                 \
    do {                                                                       \
        float4 rv = rv4[(c) * 64 + lane];                                      \
        float w0, w1, w2, w3, u0, u1, u2, u3;                                  \
        asm volatile("v_accvgpr_read_b32 %0, a" #A0 "\n\t"                     \
                     "v_accvgpr_read_b32 %1, a" #A1 "\n\t"                     \
                     "v_accvgpr_read_b32 %2, a" #A2 "\n\t"                     \
                     "v_accvgpr_read_b32 %3, a" #A3 "\n\t"                     \
                     "v_accvgpr_read_b32 %4, a" #B0 "\n\t"                     \
                     "v_accvgpr_read_b32 %5, a" #B1 "\n\t"                     \
                     "v_accvgpr_read_b32 %6, a" #B2 "\n\t"                     \
                     "v_accvgpr_read_b32 %7, a" #B3                            \
                     : "=v"(w0), "=v"(w1), "=v"(w2), "=v"(w3),                 \
                       "=v"(u0), "=v"(u1), "=v"(u2), "=v"(u3));                \
        accA.x = fmaf(w0, rv.x, accA.x);                                       \
        accA.y = fmaf(w1, rv.y, accA.y);                                       \
        accA.z = fmaf(w2, rv.z, accA.z);                                       \
        accA.w = fmaf(w3, rv.w, accA.w);                                       \
        accB.x = fmaf(u0, rv.x, accB.x);                                       \
        accB.y = fmaf(u1, rv.y, accB.y);                                       \
        accB.z = fmaf(u2, rv.z, accB.z);                                       \
        accB.w = fmaf(u3, rv.w, accB.w);                                       \
    } while (0)

// Poll this thread's 4 producer flags until all >= texp (all 4 loads issued
// up-front so a single fabric round-trip covers the common case).
#define POLL4(texp)                                                            \
    {                                                                          \
        const int f0 = tid >> 3;                                               \
        int p0 = __hip_atomic_load(flags + f0,       __ATOMIC_RELAXED, AGENT); \
        int p1 = __hip_atomic_load(flags + f0 +  64, __ATOMIC_RELAXED, AGENT); \
        int p2 = __hip_atomic_load(flags + f0 + 128, __ATOMIC_RELAXED, AGENT); \
        int p3 = __hip_atomic_load(flags + f0 + 192, __ATOMIC_RELAXED, AGENT); \
        while (p0 < (texp)) { __builtin_amdgcn_s_sleep(1);                     \
            p0 = __hip_atomic_load(flags + f0,       __ATOMIC_RELAXED, AGENT);}\
        while (p1 < (texp)) { __builtin_amdgcn_s_sleep(1);                     \
            p1 = __hip_atomic_load(flags + f0 +  64, __ATOMIC_RELAXED, AGENT);}\
        while (p2 < (texp)) { __builtin_amdgcn_s_sleep(1);                     \
            p2 = __hip_atomic_load(flags + f0 + 128, __ATOMIC_RELAXED, AGENT);}\
        while (p3 < (texp)) { __builtin_amdgcn_s_sleep(1);                     \
            p3 = __hip_atomic_load(flags + f0 + 192, __ATOMIC_RELAXED, AGENT);}\
    }                                                                          \
    asm volatile("" ::: "memory");  /* keep payload loads after the polls */

__global__ __launch_bounds__(N_THR, 2)
void esn_persistent(const float* __restrict__ batch,
                    const float* __restrict__ Win,
                    const float* __restrict__ W,
                    const float* __restrict__ Wout,
                    float* __restrict__ out,
                    float* __restrict__ rbuf,
                    int*   __restrict__ flags)
{
    __shared__ __align__(16) float r_lds[R_DIM];   // current r(t)
    __shared__ float b_lds[T_STEPS];               // input sequence
    __shared__ float psum_lds[8];                  // WG0 pred partials

    const int tid  = threadIdx.x;
    const int wid  = blockIdx.x;
    const int wave = tid >> 6;
    const int lane = tid & 63;
    const int rowA = wid * ROWS_PER_WG + wave * 2; // this wave's two W rows
    const int rowB = rowA + 1;

    for (int i = tid; i < R_DIM; i += N_THR) r_lds[i] = 0.0f;   // r(0) = 0
    for (int i = tid; i < T_STEPS; i += N_THR) b_lds[i] = batch[i];

    // Pin W rows in physical AGPRs. Lane's chunk c covers k = c*256 + lane*4.
    {
        const float4* pA = reinterpret_cast<const float4*>(W + (size_t)rowA * R_DIM);
        const float4* pB = reinterpret_cast<const float4*>(W + (size_t)rowB * R_DIM);
        float4 v;
        v = pA[ 0 * 64 + lane]; WST4(  0,   1,   2,   3, v);
        v = pA[ 1 * 64 + lane]; WST4(  4,   5,   6,   7, v);
        v = pA[ 2 * 64 + lane]; WST4(  8,   9,  10,  11, v);
        v = pA[ 3 * 64 + lane]; WST4( 12,  13,  14,  15, v);
        v = pA[ 4 * 64 + lane]; WST4( 16,  17,  18,  19, v);
        v = pA[ 5 * 64 + lane]; WST4( 20,  21,  22,  23, v);
        v = pA[ 6 * 64 + lane]; WST4( 24,  25,  26,  27, v);
        v = pA[ 7 * 64 + lane]; WST4( 28,  29,  30,  31, v);
        v = pA[ 8 * 64 + lane]; WST4( 32,  33,  34,  35, v);
        v = pA[ 9 * 64 + lane]; WST4( 36,  37,  38,  39, v);
        v = pA[10 * 64 + lane]; WST4( 40,  41,  42,  43, v);
        v = pA[11 * 64 + lane]; WST4( 44,  45,  46,  47, v);
        v = pA[12 * 64 + lane]; WST4( 48,  49,  50,  51, v);
        v = pA[13 * 64 + lane]; WST4( 52,  53,  54,  55, v);
        v = pA[14 * 64 + lane]; WST4( 56,  57,  58,  59, v);
        v = pA[15 * 64 + lane]; WST4( 60,  61,  62,  63, v);
        v = pB[ 0 * 64 + lane]; WST4( 64,  65,  66,  67, v);
        v = pB[ 1 * 64 + lane]; WST4( 68,  69,  70,  71, v);
        v = pB[ 2 * 64 + lane]; WST4( 72,  73,  74,  75, v);
        v = pB[ 3 * 64 + lane]; WST4( 76,  77,  78,  79, v);
        v = pB[ 4 * 64 + lane]; WST4( 80,  81,  82,  83, v);
        v = pB[ 5 * 64 + lane]; WST4( 84,  85,  86,  87, v);
        v = pB[ 6 * 64 + lane]; WST4( 88,  89,  90,  91, v);
        v = pB[ 7 * 64 + lane]; WST4( 92,  93,  94,  95, v);
        v = pB[ 8 * 64 + lane]; WST4( 96,  97,  98,  99, v);
        v = pB[ 9 * 64 + lane]; WST4(100, 101, 102, 103, v);
        v = pB[10 * 64 + lane]; WST4(104, 105, 106, 107, v);
        v = pB[11 * 64 + lane]; WST4(108, 109, 110, 111, v);
        v = pB[12 * 64 + lane]; WST4(112, 113, 114, 115, v);
        v = pB[13 * 64 + lane]; WST4(116, 117, 118, 119, v);
        v = pB[14 * 64 + lane]; WST4(120, 121, 122, 123, v);
        v = pB[15 * 64 + lane]; WST4(124, 125, 126, 127, v);
    }
    const float winA0 = Win[2 * rowA], winA1 = Win[2 * rowA + 1];
    const float winB0 = Win[2 * rowB], winB1 = Win[2 * rowB + 1];

    __syncthreads();

    const float4* rv4 = reinterpret_cast<const float4*>(r_lds);
    ull* r_lds8 = reinterpret_cast<ull*>(r_lds);

    for (int t = 0; t < T_STEPS; ++t) {
        if (t > 0) {
            POLL4(t);
            // Stage own 4 units (each validated by its producer's flag above).
            const ull* src8 = reinterpret_cast<const ull*>(rbuf) + (size_t)(t & 1) * (R_DIM / 2);
            ull u0 = __hip_atomic_load(src8 + tid + 0 * 512, __ATOMIC_RELAXED, AGENT);
            ull u1 = __hip_atomic_load(src8 + tid + 1 * 512, __ATOMIC_RELAXED, AGENT);
            ull u2 = __hip_atomic_load(src8 + tid + 2 * 512, __ATOMIC_RELAXED, AGENT);
            ull u3 = __hip_atomic_load(src8 + tid + 3 * 512, __ATOMIC_RELAXED, AGENT);
            r_lds8[tid + 0 * 512] = u0;
            r_lds8[tid + 1 * 512] = u1;
            r_lds8[tid + 2 * 512] = u2;
            r_lds8[tid + 3 * 512] = u3;
            __syncthreads();   // barrier A: r(t) staged; WG collectively saw ALL flags >= t
        }

        // y = W r(t) for this wave's two rows (W in AGPRs, r broadcast from LDS).
        float4 accA = make_float4(0.f, 0.f, 0.f, 0.f);
        float4 accB = make_float4(0.f, 0.f, 0.f, 0.f);
        MV2( 0,   0,   1,   2,   3,  64,  65,  66,  67);
        MV2( 1,   4,   5,   6,   7,  68,  69,  70,  71);
        MV2( 2,   8,   9,  10,  11,  72,  73,  74,  75);
        MV2( 3,  12,  13,  14,  15,  76,  77,  78,  79);
        MV2( 4,  16,  17,  18,  19,  80,  81,  82,  83);
        MV2( 5,  20,  21,  22,  23,  84,  85,  86,  87);
        MV2( 6,  24,  25,  26,  27,  88,  89,  90,  91);
        MV2( 7,  28,  29,  30,  31,  92,  93,  94,  95);
        MV2( 8,  32,  33,  34,  35,  96,  97,  98,  99);
        MV2( 9,  36,  37,  38,  39, 100, 101, 102, 103);
        MV2(10,  40,  41,  42,  43, 104, 105, 106, 107);
        MV2(11,  44,  45,  46,  47, 108, 109, 110, 111);
        MV2(12,  48,  49,  50,  51, 112, 113, 114, 115);
        MV2(13,  52,  53,  54,  55, 116, 117, 118, 119);
        MV2(14,  56,  57,  58,  59, 120, 121, 122, 123);
        MV2(15,  60,  61,  62,  63, 124, 125, 126, 127);

        float sA = (accA.x + accA.y) + (accA.z + accA.w);
        float sB = (accB.x + accB.y) + (accB.z + accB.w);
        #pragma unroll
        for (int m = 1; m < 64; m <<= 1) {
            sA += __shfl_xor(sA, m);
            sB += __shfl_xor(sB, m);
        }

        // Publish r(t+1) rows (paired 8B store). Safe vs ping-pong overwrite:
        // we are past barrier A, i.e. the whole WG verified all flags >= t,
        // so every WG has finished reading r(t-1) from this buffer.
        if (lane == 0) {
            float bt = b_lds[t];
            float xA = fast_tanh(sA + fmaf(winA1, bt, winA0));
            float xB = fast_tanh(sB + fmaf(winB1, bt, winB0));
            float rnA = 0.5f * (r_lds[rowA] + xA);
            float rnB = 0.5f * (r_lds[rowB] + xB);
            ull pack = ((ull)__float_as_uint(rnB) << 32) | __float_as_uint(rnA);
            ull* dst = reinterpret_cast<ull*>(rbuf) + (size_t)((t + 1) & 1) * (R_DIM / 2) + (rowA >> 1);
            __hip_atomic_store(dst, pack, __ATOMIC_RELAXED, AGENT);
        }

        // WG0: pred[t-1] partials over this wave's 512-element slice of r(t)
        // (before barrier B so tid0 can finalize after it, off the critical path).
        if (wid == 0 && t >= 1) {
            const float* wr = Wout + 2;
            float s = 0.0f;
            #pragma unroll
            for (int cc = 0; cc < 2; ++cc) {
                int c = wave * 2 + cc;
                int k = c * 256 + lane * 4;
                float2 wa = *reinterpret_cast<const float2*>(wr + k);
                float2 wb = *reinterpret_cast<const float2*>(wr + k + 2);
                float4 rv = rv4[c * 64 + lane];
                s = fmaf(wa.x, rv.x, s);
                s = fmaf(wa.y, rv.y, s);
                s = fmaf(wb.x, rv.z, s);
                s = fmaf(wb.y, rv.w, s);
            }
            #pragma unroll
            for (int m = 1; m < 64; m <<= 1) s += __shfl_xor(s, m);
            if (lane == 0) psum_lds[wave] = s;
        }

        __syncthreads();   // barrier B: drains all waves' r-stores (vmcnt(0))
        if (tid == 0)
            __hip_atomic_store(&flags[wid], t + 1, __ATOMIC_RELAXED, AGENT);

        // Finalize pred[t-1] after the flag publish (overlaps other WGs' detection).
        if (wid == 0 && tid == 0 && t >= 1) {
            float s = ((psum_lds[0] + psum_lds[1]) + (psum_lds[2] + psum_lds[3]))
                    + ((psum_lds[4] + psum_lds[5]) + (psum_lds[6] + psum_lds[7]));
            out[t - 1] = s + fmaf(Wout[1], b_lds[t - 1], Wout[0]);
        }
    }

    // Epilogue (WG0 only): out[T-1] from r(T).
    if (wid == 0) {
        POLL4(T_STEPS);
        const ull* src8 = reinterpret_cast<const ull*>(rbuf) + (size_t)(T_STEPS & 1) * (R_DIM / 2);
        ull u0 = __hip_atomic_load(src8 + tid + 0 * 512, __ATOMIC_RELAXED, AGENT);
        ull u1 = __hip_atomic_load(src8 + tid + 1 * 512, __ATOMIC_RELAXED, AGENT);
        ull u2 = __hip_atomic_load(src8 + tid + 2 * 512, __ATOMIC_RELAXED, AGENT);
        ull u3 = __hip_atomic_load(src8 + tid + 3 * 512, __ATOMIC_RELAXED, AGENT);
        r_lds8[tid + 0 * 512] = u0;
        r_lds8[tid + 1 * 512] = u1;
        r_lds8[tid + 2 * 512] = u2;
        r_lds8[tid + 3 * 512] = u3;
        __syncthreads();
        if (wave == 0) {
            const float* wr = Wout + 2;
            float s = 0.0f;
            #pragma unroll
            for (int c = 0; c < K_CHUNKS; ++c) {
                int k = c * 256 + lane * 4;
                float2 wa = *reinterpret_cast<const float2*>(wr + k);
                float2 wb = *reinterpret_cast<const float2*>(wr + k + 2);
                float4 rv = rv4[c * 64 + lane];
                s = fmaf(wa.x, rv.x, s);
                s = fmaf(wa.y, rv.y, s);
                s = fmaf(wb.x, rv.z, s);
                s = fmaf(wb.y, rv.w, s);
            }
            #pragma unroll
            for (int m = 1; m < 64; m <<= 1) s += __shfl_xor(s, m);
            if (lane == 0)
                out[T_STEPS - 1] = s + fmaf(Wout[1], b_lds[T_STEPS - 1], Wout[0]);
        }
    }
}

extern "C" void kernel_launch(void* const* d_in, const int* in_sizes, int n_in,
                              void* d_out, int out_size, void* d_ws, size_t ws_size,
                              hipStream_t stream) {
    (void)in_sizes; (void)n_in; (void)out_size; (void)ws_size;
    const float* batch = (const float*)d_in[0];   // (1024,1,1)
    const float* Win   = (const float*)d_in[1];   // (4096,2) row-major
    const float* W     = (const float*)d_in[2];   // (4096,4096) row-major
    const float* Wout  = (const float*)d_in[3];   // (1,4098)
    float* out  = (float*)d_out;                  // (1024,1)
    float* rbuf = (float*)d_ws;                                   // 2*4096 floats
    int*   flags = (int*)((char*)d_ws + 2 * R_DIM * sizeof(float)); // 256 ints

    // flags must start < 1 every launch (d_ws is not re-poisoned between replays).
    hipMemsetAsync(flags, 0, N_WG * sizeof(int), stream);

    // grid=256 WGs x 512 thr (8 waves = 2 waves/SIMD; 128 AGPR + ~96 VGPR fits).
    // grid == CU count => all WGs co-resident for the spin barrier.
    esn_persistent<<<dim3(N_WG), dim3(N_THR), 0, stream>>>(
        batch, Win, W, Wout, out, rbuf, flags);
}